// Round 5
// baseline (202.100 us; speedup 1.0000x reference)
//
#include <hip/hip_runtime.h>
#include <hip/hip_bf16.h>
#include <math.h>

#define BDIM 8192
#define DDIM 2048
#define CDIM 1000
#define BK   64

// ws layout (bytes):
//   Bt bf16 [1024*2048] =  4194304 @ 0
//   P0 bf16 [8192*1000] = 16384000 @ 4194304    (split-K partial, k-half 0)
//   P1 bf16 [8192*1000] = 16384000 @ 20578304   (split-K partial, k-half 1)
#define WS_P0_OFFSET  4194304ULL
#define WS_P1_OFFSET  20578304ULL

typedef __attribute__((ext_vector_type(8))) short short8;
typedef __attribute__((ext_vector_type(4))) float floatx4;

__device__ __forceinline__ unsigned short f2bf(float f) {
    union { float f; unsigned u; } a; a.f = f;
    unsigned u = a.u;
    u = (u + 0x7fff + ((u >> 16) & 1)) >> 16;   // RNE, finite inputs
    return (unsigned short)u;
}

__device__ __forceinline__ float bf2f(unsigned short h) {
    union { unsigned u; float f; } a; a.u = ((unsigned)h) << 16;
    return a.f;
}

__device__ __forceinline__ void async_copy16(const void* gp, void* lp) {
    __builtin_amdgcn_global_load_lds(
        (const __attribute__((address_space(1))) void*)gp,
        (__attribute__((address_space(3))) void*)lp,
        16, 0, 0);
}

// ---- kernel 1: W -> Bt transpose only (x-conversion fused into GEMM) ----
__global__ __launch_bounds__(256) void cvt_w_kernel(
    const float* __restrict__ W, unsigned short* __restrict__ Bt)
{
    __shared__ float tile[32][33];
    const int b2 = blockIdx.x;           // 64 k-tiles x 32 n-tiles
    const int t  = threadIdx.x;
    const int k0 = (b2 & 63) * 32;
    const int n0 = (b2 >> 6) * 32;
    const int tx = t & 31, ty = t >> 5;  // 32 x 8
    #pragma unroll
    for (int i = 0; i < 4; i++) {
        int k = k0 + ty + i * 8;
        int n = n0 + tx;
        tile[ty + i * 8][tx] = (n < CDIM) ? W[(size_t)k * CDIM + n] : 0.0f;
    }
    __syncthreads();
    #pragma unroll
    for (int i = 0; i < 4; i++) {
        int n = n0 + ty + i * 8;
        int k = k0 + tx;
        Bt[(size_t)n * DDIM + k] = f2bf(tile[tx][ty + i * 8]);
    }
}

// =====================================================================
// 4-region 256x256 split-K GEMM, fused A-conversion, DEEP COVER (R5).
// A staged global(f32)->reg->cvt->LDS in 4 parts/tile (part p = rows
// q0 + (p>>1)*64 + (p&1)*128, one 16B chunk per thread).  Part p of
// tile j+2 is WRITTEN at phase p of iter j (right after its LDS rows'
// readers completed) and part p of tile j+3 is ISSUED immediately
// after (write-then-issue => WAR keeps one 8-reg slot per part).
// Issue pattern per iter (12 vmem ops, FIFO):
//   q0: A-p0x2 | q1: B-u0x2, A-p1x2 | q2: B-u1x2, A-p2x2 | q3: A-p3x2
// Steady outstanding entering each phase's wait = 12; retiring the
// 2-op (q0/q3) or 4-op (q1/q2) head each phase => UNIFORM vmcnt(10).
// Cover: each A part 4 phases, B units 5-7 phases.  Tail: source
// indices clamp to the last tile (harmless re-loads into quarters
// never read again) so counts stay uniform.
// Hazard edges (>=1 barrier after readers complete, all verified):
//   p0/p1 overwrite af0 rows (read q3(j-1), lgkm0'd); p2/p3 overwrite
//   af1 rows (consumed by MMAC(1,0)/(1,1) issue earlier same phase);
//   B-u0 overwrites bf0 rows (LDS-read done q3(j-1)); B-u1 overwrites
//   bf1 rows (read q0, consumed from regs only afterwards).
// =====================================================================

#define HBUF (256 * BK)   // ushorts per buffer half (32 KiB)

#define STAGE_B2(BASE, EXT, KO)                                               \
    do {                                                                      \
        _Pragma("unroll")                                                     \
        for (int h = 0; h < 2; h++) {                                         \
            const int row_ = rB0 + (EXT) + h * 128;                           \
            async_copy16(gB + (size_t)row_ * DDIM + (KO),                     \
                         (BASE) + row_ * BK + c8);                            \
        }                                                                     \
    } while (0)

// issue part P (rows q0 + (P>>1)*64 + (P&1)*128): 2 float4 loads
#define ISSUE_P(P, KO)                                                        \
    do {                                                                      \
        const float* p_ = gAf +                                               \
            (size_t)(q0 + ((P) >> 1) * 64 + ((P) & 1) * 128) * DDIM + (KO);   \
        ax[P][0] = *(const float4*)(p_);                                      \
        ax[P][1] = *(const float4*)(p_ + 4);                                  \
    } while (0)

// convert part P and store to swizzled LDS chunk
#define WRITE_P(BASE, P)                                                      \
    do {                                                                      \
        const int row_ = q0 + ((P) >> 1) * 64 + ((P) & 1) * 128;              \
        float4 lo_ = ax[P][0];                                                \
        float4 hi_ = ax[P][1];                                                \
        short8 pk_;                                                           \
        pk_[0] = (short)f2bf(lo_.x); pk_[1] = (short)f2bf(lo_.y);             \
        pk_[2] = (short)f2bf(lo_.z); pk_[3] = (short)f2bf(lo_.w);             \
        pk_[4] = (short)f2bf(hi_.x); pk_[5] = (short)f2bf(hi_.y);             \
        pk_[6] = (short)f2bf(hi_.z); pk_[7] = (short)f2bf(hi_.w);             \
        *(short8*)((BASE) + row_ * BK + csw) = pk_;                           \
    } while (0)

#define LOADA_(BASE, MQ)                                                      \
    do {                                                                      \
        _Pragma("unroll")                                                     \
        for (int mf = 0; mf < 4; mf++) {                                      \
            const int r_ = (arA + (MQ) * 64 + mf * 16) * BK;                  \
            af[mf][0] = *(const short8*)((BASE) + r_ + xorb0);                \
            af[mf][1] = *(const short8*)((BASE) + r_ + xorb1);                \
        }                                                                     \
    } while (0)

#define LOADB_(BASE, NQ, BF)                                                  \
    do {                                                                      \
        _Pragma("unroll")                                                     \
        for (int nf = 0; nf < 2; nf++) {                                      \
            const int r_ = (arB + (NQ) * 32 + nf * 16) * BK;                  \
            BF[nf][0] = *(const short8*)((BASE) + r_ + xorb0);                \
            BF[nf][1] = *(const short8*)((BASE) + r_ + xorb1);                \
        }                                                                     \
    } while (0)

#define MMAC(MQ, NQ, BF)                                                      \
    do {                                                                      \
        __builtin_amdgcn_s_setprio(1);                                        \
        _Pragma("unroll")                                                     \
        for (int mf = 0; mf < 4; mf++) {                                      \
            _Pragma("unroll")                                                 \
            for (int nf = 0; nf < 2; nf++) {                                  \
                floatx4 c_ = acc[(MQ) * 4 + mf][(NQ) * 2 + nf];               \
                c_ = __builtin_amdgcn_mfma_f32_16x16x32_bf16(                 \
                    af[mf][0], BF[nf][0], c_, 0, 0, 0);                       \
                c_ = __builtin_amdgcn_mfma_f32_16x16x32_bf16(                 \
                    af[mf][1], BF[nf][1], c_, 0, 0, 0);                       \
                acc[(MQ) * 4 + mf][(NQ) * 2 + nf] = c_;                       \
            }                                                                 \
        }                                                                     \
        __builtin_amdgcn_s_setprio(0);                                        \
    } while (0)

#define RAW_BARRIER() asm volatile("s_barrier" ::: "memory")
#define WAIT_VM(N)    asm volatile("s_waitcnt vmcnt(" #N ")" ::: "memory")
#define WAIT_LGKM0()  asm volatile("s_waitcnt lgkmcnt(0)" ::: "memory")

__global__ __launch_bounds__(512, 2) void gemm8_kernel(
    const float* __restrict__ X,
    const unsigned short* __restrict__ Bt,
    unsigned short* __restrict__ P0, unsigned short* __restrict__ P1)
{
    __shared__ unsigned short As[2 * HBUF];
    __shared__ unsigned short Bs[2 * HBUF];

    const int t    = threadIdx.x;
    const int wave = t >> 6;
    const int lane = t & 63;
    const int wm   = wave >> 2;          // 0..1  (M half)
    const int wn   = wave & 3;           // 0..3  (N quarter)
    const int quad = lane >> 4;
    const int l16  = lane & 15;

    // XCD-swizzled block mapping: 256 blocks -> 8 XCDs x 32.
    const int L    = blockIdx.x;
    const int g    = (L & 7) * 32 + (L >> 3);   // bijective, nwg%8==0
    const int z    = g & 1;                     // K-split
    const int tid2 = g >> 1;                    // 0..127
    const int mBase = (tid2 >> 2) * 256;
    const int nBase = (tid2 & 3) * 256;
    const int kBase = z * (DDIM / 2);
    const int NTt   = (DDIM / 2) / BK;          // 16 K-tiles

    // --- staging precompute
    const int c8  = (t & 7) << 3;               // B dst chunk col (ushorts)
    const int q0  = t >> 3;                     // 0..63
    const int csw = (((t & 7) ^ (q0 & 7)) << 3);// swizzled chunk (A dst / B src)
    const int rB0 = q0 + (q0 & 32);             // B-u0 rows: rb, rb+128
    const float* gAf = X + (size_t)mBase * DDIM + kBase + ((t & 7) << 3);
    const unsigned short* gB = Bt + (size_t)nBase * DDIM + kBase + csw;

    // --- fragment-read precompute
    const int xorb0 = ((0 * 4 + quad) ^ (l16 & 7)) << 3;
    const int xorb1 = ((1 * 4 + quad) ^ (l16 & 7)) << 3;
    const int arA = wm * 128 + l16;
    const int arB = wn * 64 + l16;

    floatx4 acc[8][4] = {};
    short8 af[4][2], bf0[2][2], bf1[2][2];
    float4 ax[4][2];

    // --- prologue ---
    // tile0 A: issue all 4 parts, drain, write.
    ISSUE_P(0, 0); ISSUE_P(1, 0); ISSUE_P(2, 0); ISSUE_P(3, 0);
    WAIT_VM(0);
    WRITE_P(As, 0); WRITE_P(As, 1); WRITE_P(As, 2); WRITE_P(As, 3);
    // tile1 A issue, then B(0) gload; wait A(1) (FIFO [A1 x8, B0 x4]).
    ISSUE_P(0, BK); ISSUE_P(1, BK); ISSUE_P(2, BK); ISSUE_P(3, BK);
    STAGE_B2(Bs, 0, 0);
    STAGE_B2(Bs, 32, 0);
    WAIT_VM(4);
    WRITE_P(As + HBUF, 0); WRITE_P(As + HBUF, 1);
    WRITE_P(As + HBUF, 2); WRITE_P(As + HBUF, 3);
    // steady-state issue pattern for tile2 A + tile1 B:
    //   [p0(2), Bu0(1), p1(2), Bu1(1), p2(2), p3(2)]  (+B0 x4 older)
    ISSUE_P(0, 2 * BK);
    STAGE_B2(Bs + HBUF, 0, BK);
    ISSUE_P(1, 2 * BK);
    STAGE_B2(Bs + HBUF, 32, BK);
    ISSUE_P(2, 2 * BK);
    ISSUE_P(3, 2 * BK);
    WAIT_VM(12);                 // retires B(0); steady FIFO of 12 remains
    WAIT_LGKM0();
    RAW_BARRIER();
    LOADA_(As, 0);
    LOADB_(Bs, 0, bf0);
    WAIT_LGKM0();
    RAW_BARRIER();

    for (int j = 0; j < NTt; j++) {
        const int bo = (j & 1) * HBUF;
        unsigned short* const cA = (unsigned short*)As + bo;
        unsigned short* const cB = (unsigned short*)Bs + bo;
        const unsigned short* const nA = (const unsigned short*)As + (bo ^ HBUF);
        const unsigned short* const nB = (const unsigned short*)Bs + (bo ^ HBUF);
        const int koB = (j + 2 < NTt ? j + 2 : NTt - 1) * BK;  // clamped
        const int koA = (j + 3 < NTt ? j + 3 : NTt - 1) * BK;  // clamped

        // q0: MFMA(0,0); read bf1(j); wait; write A-p0(j+2); issue A-p0(j+3)
        MMAC(0, 0, bf0);
        LOADB_(cB, 1, bf1);
        WAIT_VM(10);
        WRITE_P(cA, 0);
        ISSUE_P(0, koA);
        RAW_BARRIER();

        // q1: gload B-u0(j+2); MFMA(0,1); read af1(j); wait; write p1; issue p1
        STAGE_B2(cB, 0, koB);
        MMAC(0, 1, bf1);
        LOADA_(cA, 1);
        WAIT_VM(10);
        WRITE_P(cA, 1);
        ISSUE_P(1, koA);
        RAW_BARRIER();

        // q2: gload B-u1(j+2); MFMA(1,0); wait (confirms all B(j+1));
        //     write p2; issue p2
        STAGE_B2(cB, 32, koB);
        MMAC(1, 0, bf0);
        WAIT_VM(10);
        WRITE_P(cA, 2);
        ISSUE_P(2, koA);
        RAW_BARRIER();

        // q3: MFMA(1,1); wait; write p3; issue p3; pre-read tile j+1
        MMAC(1, 1, bf1);
        WAIT_VM(10);
        WRITE_P(cA, 3);
        ISSUE_P(3, koA);
        if (j + 1 < NTt) { LOADA_(nA, 0); LOADB_(nB, 0, bf0); }
        WAIT_LGKM0();
        RAW_BARRIER();
    }
    WAIT_VM(0);   // drain clamped tail loads before exit

    // --- epilogue: bf16 partial store (C row = quad*4+reg, col = l16)
    unsigned short* P = z ? P1 : P0;
    #pragma unroll
    for (int mfg = 0; mfg < 8; mfg++) {
        const int row0 = mBase + wm * 128 + mfg * 16 + quad * 4;
        #pragma unroll
        for (int nfg = 0; nfg < 4; nfg++) {
            const int col = nBase + wn * 64 + nfg * 16 + l16;
            if (col < CDIM) {
                #pragma unroll
                for (int rg = 0; rg < 4; rg++)
                    P[(size_t)(row0 + rg) * CDIM + col] = f2bf(acc[mfg][nfg][rg]);
            }
        }
    }
}

// ---- bias + LOO-logsumexp; sums two bf16 partials -> fp32 out ----
__global__ __launch_bounds__(256) void lse_kernel(
    float* __restrict__ out,
    const unsigned short* P0, const unsigned short* P1,
    const float* __restrict__ bias)
{
    const int row = blockIdx.x;
    const int t   = threadIdx.x;
    __shared__ float red[8];

    const bool valid = t < (CDIM / 4);   // 250 threads x 4 cols
    const int c0 = t * 4;

    float4 v = make_float4(-INFINITY, -INFINITY, -INFINITY, -INFINITY);
    float4 e = make_float4(0.f, 0.f, 0.f, 0.f);
    if (valid) {
        ushort4 p0 = *(const ushort4*)(P0 + (size_t)row * CDIM + c0);
        ushort4 p1 = *(const ushort4*)(P1 + (size_t)row * CDIM + c0);
        v.x = bf2f(p0.x) + bf2f(p1.x);
        v.y = bf2f(p0.y) + bf2f(p1.y);
        v.z = bf2f(p0.z) + bf2f(p1.z);
        v.w = bf2f(p0.w) + bf2f(p1.w);
        float4 bb = *(const float4*)(bias + c0);
        v.x += bb.x; v.y += bb.y; v.z += bb.z; v.w += bb.w;
    }

    float m = fmaxf(fmaxf(v.x, v.y), fmaxf(v.z, v.w));
    #pragma unroll
    for (int off = 32; off > 0; off >>= 1)
        m = fmaxf(m, __shfl_down(m, off, 64));
    const int wave = t >> 6;
    if ((t & 63) == 0) red[wave] = m;
    __syncthreads();
    if (t == 0) red[4] = fmaxf(fmaxf(red[0], red[1]), fmaxf(red[2], red[3]));
    __syncthreads();
    const float M = red[4];

    float s = 0.f;
    if (valid) {
        e.x = expf(v.x - M); e.y = expf(v.y - M);
        e.z = expf(v.z - M); e.w = expf(v.w - M);
        s = e.x + e.y + e.z + e.w;
    }
    #pragma unroll
    for (int off = 32; off > 0; off >>= 1)
        s += __shfl_down(s, off, 64);
    if ((t & 63) == 0) red[wave] = s;
    __syncthreads();
    if (t == 0) red[4] = red[0] + red[1] + red[2] + red[3];
    __syncthreads();
    const float S    = red[4];
    const float lse  = M + logf(S);
    const float invS = 1.0f / S;

    if (valid) {
        float4 o;
        o.x = (v.x - lse) - log1pf(-e.x * invS);
        o.y = (v.y - lse) - log1pf(-e.y * invS);
        o.z = (v.z - lse) - log1pf(-e.z * invS);
        o.w = (v.w - lse) - log1pf(-e.w * invS);
        *(float4*)(out + (size_t)row * CDIM + c0) = o;
    }
}

extern "C" void kernel_launch(void* const* d_in, const int* in_sizes, int n_in,
                              void* d_out, int out_size, void* d_ws, size_t ws_size,
                              hipStream_t stream) {
    const float* x = (const float*)d_in[0];   // [8192, 2048]
    const float* W = (const float*)d_in[1];   // [2048, 1000]
    const float* b = (const float*)d_in[2];   // [1000]
    float* out = (float*)d_out;               // [8192, 1000]

    unsigned short* Bt = (unsigned short*)d_ws;
    unsigned short* P0 = (unsigned short*)((char*)d_ws + WS_P0_OFFSET);
    unsigned short* P1 = (unsigned short*)((char*)d_ws + WS_P1_OFFSET);

    // 1) W -> Bt transpose (x-conversion fused into the GEMM)
    cvt_w_kernel<<<2048, 256, 0, stream>>>(W, Bt);

    // 2) split-K GEMM reading x (f32) directly, deep-cover reg staging
    gemm8_kernel<<<256, 512, 0, stream>>>(x, Bt, P0, P1);

    // 3) bias + LOO-LSE from the two bf16 partials
    lse_kernel<<<BDIM, 256, 0, stream>>>(out, P0, P1, b);
}

// Round 7
// 174.293 us; speedup vs baseline: 1.1595x; 1.1595x over previous
//
#include <hip/hip_runtime.h>
#include <hip/hip_bf16.h>
#include <math.h>

#define BDIM 8192
#define DDIM 2048
#define CDIM 1000
#define NPAD 1024
#define BK   64

// ws layout (bytes):
//   xb bf16 [8192*2048] = 33554432 @ 0
//   Bt bf16 [1024*2048] =  4194304 @ 33554432
//   P0 bf16 [8192*1000] = 16384000 @ 37748736   (split-K partial, k-half 0)
//   P1 bf16 [8192*1000] = 16384000 @ 54132736   (split-K partial, k-half 1)
// total = 70516736
#define WS_BT_OFFSET  33554432ULL
#define WS_P0_OFFSET  37748736ULL
#define WS_P1_OFFSET  54132736ULL
#define WS_NEED       70516736ULL

typedef __attribute__((ext_vector_type(8))) short short8;
typedef __attribute__((ext_vector_type(4))) float floatx4;

__device__ __forceinline__ unsigned short f2bf(float f) {
    union { float f; unsigned u; } a; a.f = f;
    unsigned u = a.u;
    u = (u + 0x7fff + ((u >> 16) & 1)) >> 16;   // RNE, finite inputs
    return (unsigned short)u;
}

__device__ __forceinline__ float bf2f(unsigned short h) {
    union { unsigned u; float f; } a; a.u = ((unsigned)h) << 16;
    return a.f;
}

__device__ __forceinline__ void async_copy16(const void* gp, void* lp) {
    __builtin_amdgcn_global_load_lds(
        (const __attribute__((address_space(1))) void*)gp,
        (__attribute__((address_space(3))) void*)lp,
        16, 0, 0);
}

// ---- kernel 1: fused x->bf16 (blocks 0..16383) and W->Bt transpose (blocks 16384..18431) ----
__global__ __launch_bounds__(256) void cvt_kernel(
    const float* __restrict__ x, unsigned short* __restrict__ xb,
    const float* __restrict__ W, unsigned short* __restrict__ Bt)
{
    const int blk = blockIdx.x;
    const int t   = threadIdx.x;
    if (blk < 16384) {
        int i = blk * 256 + t;
        float4 v = ((const float4*)x)[i];
        ushort4 o;
        o.x = f2bf(v.x); o.y = f2bf(v.y); o.z = f2bf(v.z); o.w = f2bf(v.w);
        ((ushort4*)xb)[i] = o;
    } else {
        __shared__ float tile[32][33];
        const int b2 = blk - 16384;          // 64 k-tiles x 32 n-tiles
        const int k0 = (b2 & 63) * 32;
        const int n0 = (b2 >> 6) * 32;
        const int tx = t & 31, ty = t >> 5;  // 32 x 8
        #pragma unroll
        for (int i = 0; i < 4; i++) {
            int k = k0 + ty + i * 8;
            int n = n0 + tx;
            tile[ty + i * 8][tx] = (n < CDIM) ? W[(size_t)k * CDIM + n] : 0.0f;
        }
        __syncthreads();
        #pragma unroll
        for (int i = 0; i < 4; i++) {
            int n = n0 + ty + i * 8;
            int k = k0 + tx;
            Bt[(size_t)n * DDIM + k] = f2bf(tile[tx][ty + i * 8]);
        }
    }
}

// ---- GEMM body: R7 structure (XOR-swizzled LDS, zero bank conflicts) ----
// BF16OUT: store partials as bf16 (split-K path); else fp32 (fallback).
template <bool BF16OUT>
__device__ __forceinline__ void gemm_body(
    const unsigned short* __restrict__ A,
    const unsigned short* __restrict__ Bt,
    void* __restrict__ Cv,
    int mBase, int nBase, int kBase, int kIters,
    unsigned short* As, unsigned short* Bs)
{
    const int t    = threadIdx.x;
    const int wave = t >> 6;
    const int lane = t & 63;
    const int wm   = wave & 1;
    const int wn   = wave >> 1;
    const int quad = lane >> 4;
    const int l16  = lane & 15;

    floatx4 acc[4][4] = {};

    // staging: thread t -> dst slot (rowA = t>>3, chunk c = t&7); fetch the
    // global chunk that belongs there: c' = c ^ (rowA&7). (32r keeps R&7.)
    const int rowA = t >> 3;
    const int csw  = ((t & 7) ^ (rowA & 7)) * 16;   // swizzled source byte col
    const char* Ag = (const char*)A  + ((size_t)(mBase + rowA) * DDIM + kBase) * 2 + csw;
    const char* Bg = (const char*)Bt + ((size_t)(nBase + rowA) * DDIM + kBase) * 2 + csw;
    char* AsDst = (char*)As + t * 16;
    char* BsDst = (char*)Bs + t * 16;

    // fragment-read XOR term: chunk cf = ks*4+quad, swizzled by (Rm&7)=(l16&7)
    const int xorb0 = ((0 * 4 + quad) ^ (l16 & 7)) * 8;   // ks=0, ushort units
    const int xorb1 = ((1 * 4 + quad) ^ (l16 & 7)) * 8;   // ks=1

    for (int kt = 0; kt < kIters * BK; kt += BK) {
        const char* a = Ag + kt * 2;
        const char* b = Bg + kt * 2;
        #pragma unroll
        for (int r = 0; r < 4; r++) {
            async_copy16(a + (size_t)r * 32 * DDIM * 2, AsDst + r * 4096);
            async_copy16(b + (size_t)r * 32 * DDIM * 2, BsDst + r * 4096);
        }
        __syncthreads();

        #pragma unroll
        for (int ks = 0; ks < 2; ks++) {
            const int xorb = ks ? xorb1 : xorb0;
            short8 af[4], bfr[4];
            #pragma unroll
            for (int mi = 0; mi < 4; mi++)
                af[mi] = *(const short8*)(As + (wm * 64 + mi * 16 + l16) * BK + xorb);
            #pragma unroll
            for (int ni = 0; ni < 4; ni++)
                bfr[ni] = *(const short8*)(Bs + (wn * 64 + ni * 16 + l16) * BK + xorb);
            #pragma unroll
            for (int mi = 0; mi < 4; mi++)
                #pragma unroll
                for (int ni = 0; ni < 4; ni++)
                    acc[mi][ni] = __builtin_amdgcn_mfma_f32_16x16x32_bf16(
                        af[mi], bfr[ni], acc[mi][ni], 0, 0, 0);
        }
        __syncthreads();
    }

    // C/D layout: col=lane&15, row=quad*4+reg
    #pragma unroll
    for (int mi = 0; mi < 4; mi++) {
        int row0 = mBase + wm * 64 + mi * 16 + quad * 4;
        #pragma unroll
        for (int ni = 0; ni < 4; ni++) {
            int col = nBase + wn * 64 + ni * 16 + l16;
            if (col < CDIM) {
                #pragma unroll
                for (int rg = 0; rg < 4; rg++) {
                    if (BF16OUT)
                        ((unsigned short*)Cv)[(size_t)(row0 + rg) * CDIM + col] =
                            f2bf(acc[mi][ni][rg]);
                    else
                        ((float*)Cv)[(size_t)(row0 + rg) * CDIM + col] = acc[mi][ni][rg];
                }
            }
        }
    }
}

// ---- split-K GEMM: grid 1024, XCD-swizzled; z=0 -> P0, z=1 -> P1 (bf16) ----
__global__ __launch_bounds__(256, 4) void gemm_splitk_kernel(
    const unsigned short* __restrict__ A,
    const unsigned short* __restrict__ Bt,
    unsigned short* __restrict__ P0, unsigned short* __restrict__ P1)
{
    __shared__ unsigned short As[128 * BK];
    __shared__ unsigned short Bs[128 * BK];

    const int L   = blockIdx.x;          // 0..1023
    const int xcd = L & 7;
    const int s   = L >> 3;              // 0..127
    const int mz  = xcd * 16 + (s >> 3); // 0..127
    const int n_t = s & 7;
    const int m_t = mz >> 1;             // 0..63
    const int z   = mz & 1;

    unsigned short* P = z ? P1 : P0;
    gemm_body<true>(A, Bt, P, m_t * 128, n_t * 128, z * (DDIM / 2), (DDIM / 2) / BK, As, Bs);
}

// ---- single-K fallback: grid 512, fp32 out ----
__global__ __launch_bounds__(256, 2) void gemm_single_kernel(
    const unsigned short* __restrict__ A,
    const unsigned short* __restrict__ Bt,
    float* __restrict__ C0)
{
    __shared__ unsigned short As[128 * BK];
    __shared__ unsigned short Bs[128 * BK];

    const int L   = blockIdx.x;          // 0..511
    const int xcd = L & 7;
    const int s   = L >> 3;              // 0..63
    const int m_t = xcd * 8 + (s >> 3);
    const int n_t = s & 7;

    gemm_body<false>(A, Bt, C0, m_t * 128, n_t * 128, 0, DDIM / BK, As, Bs);
}

// ---- bias + LOO-logsumexp; split: sum two bf16 partials -> fp32 out ----
__global__ __launch_bounds__(256) void lse_kernel(
    float* __restrict__ out,
    const unsigned short* P0, const unsigned short* P1,
    const float* __restrict__ bias, int split)
{
    const int row = blockIdx.x;
    const int t   = threadIdx.x;
    __shared__ float red[8];

    const bool valid = t < (CDIM / 4);   // 250 threads x 4 cols
    const int c0 = t * 4;

    float4 v = make_float4(-INFINITY, -INFINITY, -INFINITY, -INFINITY);
    float4 e = make_float4(0.f, 0.f, 0.f, 0.f);
    if (valid) {
        if (split) {
            // byte offset (row*1000+c0)*2 = 2000*row + 8*t -> 8B aligned
            ushort4 p0 = *(const ushort4*)(P0 + (size_t)row * CDIM + c0);
            ushort4 p1 = *(const ushort4*)(P1 + (size_t)row * CDIM + c0);
            v.x = bf2f(p0.x) + bf2f(p1.x);
            v.y = bf2f(p0.y) + bf2f(p1.y);
            v.z = bf2f(p0.z) + bf2f(p1.z);
            v.w = bf2f(p0.w) + bf2f(p1.w);
        } else {
            v = *(const float4*)(out + (size_t)row * CDIM + c0);
        }
        float4 bb = *(const float4*)(bias + c0);
        v.x += bb.x; v.y += bb.y; v.z += bb.z; v.w += bb.w;
    }

    float m = fmaxf(fmaxf(v.x, v.y), fmaxf(v.z, v.w));
    #pragma unroll
    for (int off = 32; off > 0; off >>= 1)
        m = fmaxf(m, __shfl_down(m, off, 64));
    const int wave = t >> 6;
    if ((t & 63) == 0) red[wave] = m;
    __syncthreads();
    if (t == 0) red[4] = fmaxf(fmaxf(red[0], red[1]), fmaxf(red[2], red[3]));
    __syncthreads();
    const float M = red[4];

    float s = 0.f;
    if (valid) {
        e.x = expf(v.x - M); e.y = expf(v.y - M);
        e.z = expf(v.z - M); e.w = expf(v.w - M);
        s = e.x + e.y + e.z + e.w;
    }
    #pragma unroll
    for (int off = 32; off > 0; off >>= 1)
        s += __shfl_down(s, off, 64);
    if ((t & 63) == 0) red[wave] = s;
    __syncthreads();
    if (t == 0) red[4] = red[0] + red[1] + red[2] + red[3];
    __syncthreads();
    const float S    = red[4];
    const float lse  = M + logf(S);
    const float invS = 1.0f / S;

    if (valid) {
        float4 o;
        o.x = (v.x - lse) - log1pf(-e.x * invS);
        o.y = (v.y - lse) - log1pf(-e.y * invS);
        o.z = (v.z - lse) - log1pf(-e.z * invS);
        o.w = (v.w - lse) - log1pf(-e.w * invS);
        *(float4*)(out + (size_t)row * CDIM + c0) = o;
    }
}

extern "C" void kernel_launch(void* const* d_in, const int* in_sizes, int n_in,
                              void* d_out, int out_size, void* d_ws, size_t ws_size,
                              hipStream_t stream) {
    const float* x = (const float*)d_in[0];   // [8192, 2048]
    const float* W = (const float*)d_in[1];   // [2048, 1000]
    const float* b = (const float*)d_in[2];   // [1000]
    float* out = (float*)d_out;               // [8192, 1000]

    unsigned short* xb = (unsigned short*)d_ws;
    unsigned short* Bt = (unsigned short*)((char*)d_ws + WS_BT_OFFSET);
    unsigned short* P0 = (unsigned short*)((char*)d_ws + WS_P0_OFFSET);
    unsigned short* P1 = (unsigned short*)((char*)d_ws + WS_P1_OFFSET);
    const bool splitk = ws_size >= WS_NEED;   // constant across calls

    // 1) fused x->bf16 + W->Bt (16384 + 2048 blocks)
    cvt_kernel<<<18432, 256, 0, stream>>>(x, xb, W, Bt);

    // 2) GEMM + 3) LOO-LSE
    if (splitk) {
        gemm_splitk_kernel<<<1024, 256, 0, stream>>>(xb, Bt, P0, P1);
        lse_kernel<<<BDIM, 256, 0, stream>>>(out, P0, P1, b, 1);
    } else {
        gemm_single_kernel<<<512, 256, 0, stream>>>(xb, Bt, out);
        lse_kernel<<<BDIM, 256, 0, stream>>>(out, nullptr, nullptr, b, 0);
    }
}